// Round 8
// baseline (19.489 us; speedup 1.0000x reference)
//
#include <hip/hip_runtime.h>
#include <math.h>

// Siddon exact forward projector — wave-uniform XY-DDA + per-lane z-blend.
// Geometry: all 64 rays in a wave (consecutive detector-v, same detector-u)
// share p0x,dx,p0y,dy EXACTLY -> x/y crossings are lockstep across the wave.
// Only z differs per lane, and |dz| < |dx| guarantees <=1 z-crossing per
// uniform xy-segment. So the loop walks uniform (ix,iy) segments; each lane
// splits the segment at its private z-crossing: dt0*v[iz] + dt1*v[iz+oz].
// Result: a wave's gathers stay inside ONE 128-float row (2-3 cachelines),
// with no lane drift — fixing the address-divergence bottleneck that made
// rounds 4-6 (latency/MLP/occupancy fixes) null.
// Per-lane z-slab clipping: each uniform segment [s0,s1) is clipped to the
// lane's [tmin_l,tmax_l]; fmaxf-clamps make dt exactly 0 outside, matching
// the reference's clamped-crossing semantics.

constexpr int      NV    = 128;
constexpr int      NVSQ  = NV * NV;
constexpr unsigned NV3   = (unsigned)NV * NV * NV;
constexpr float    EPS_F = 1e-12f;
constexpr float    BIG_F = 1e9f;
constexpr int      SPLIT = 8;    // sub-ranges per ray = waves per block
constexpr int      RPB   = 64;   // rays per block (= lanes per wave)

__global__ __launch_bounds__(512, 8)
void siddon_fwd_kernel(const float* __restrict__ vol,
                       const float* __restrict__ Mptr,
                       const float* __restrict__ bptr,
                       const float* __restrict__ src,
                       const float* __restrict__ dst,
                       float* __restrict__ out,
                       int n_ray)
{
    int lane = threadIdx.x & 63;
    int sub  = threadIdx.x >> 6;            // 0..7, one sub-range per wave

    // ---- XCD-aware block swizzle (bijective when gridDim.x % 8 == 0) ----
    int bid = blockIdx.x;
    int nwg = gridDim.x;
    int lb  = ((nwg & 7) == 0) ? ((bid & 7) * (nwg >> 3) + (bid >> 3)) : bid;

    int r = lb * RPB + lane;
    bool active = (r < n_ray);
    int rc = active ? r : (n_ray - 1);      // clamped for loads

    // ---- uniform: M inverse via adjugate ----
    float m00 = Mptr[0], m01 = Mptr[1], m02 = Mptr[2];
    float m10 = Mptr[3], m11 = Mptr[4], m12 = Mptr[5];
    float m20 = Mptr[6], m21 = Mptr[7], m22 = Mptr[8];
    float det = m00*(m11*m22 - m12*m21) - m01*(m10*m22 - m12*m20)
              + m02*(m10*m21 - m11*m20);
    float idet = 1.0f / det;
    float i00 =  (m11*m22 - m12*m21)*idet;
    float i01 = -(m01*m22 - m02*m21)*idet;
    float i02 =  (m01*m12 - m02*m11)*idet;
    float i10 = -(m10*m22 - m12*m20)*idet;
    float i11 =  (m00*m22 - m02*m20)*idet;
    float i12 = -(m00*m12 - m02*m10)*idet;
    float i20 =  (m10*m21 - m11*m20)*idet;
    float i21 = -(m00*m21 - m01*m20)*idet;
    float i22 =  (m00*m11 - m01*m10)*idet;

    float bx = bptr[0], by = bptr[1], bz = bptr[2];

    float sxw = src[3*rc+0], syw = src[3*rc+1], szw = src[3*rc+2];
    float exw = dst[3*rc+0], eyw = dst[3*rc+1], ezw = dst[3*rc+2];

    float wxw = exw - sxw, wyw = eyw - syw, wzw = ezw - szw;
    float ray_len = sqrtf(wxw*wxw + wyw*wyw + wzw*wzw);

    float ux = sxw - bx, uy = syw - by, uz = szw - bz;
    float p0x = i00*ux + i01*uy + i02*uz;
    float p0y = i10*ux + i11*uy + i12*uz;
    float p0z = i20*ux + i21*uy + i22*uz;
    float vx = exw - bx, vy = eyw - by, vz = ezw - bz;
    float p1x = i00*vx + i01*vy + i02*vz;
    float p1y = i10*vx + i11*vy + i12*vz;
    float p1z = i20*vx + i21*vy + i22*vz;

    float dx = p1x - p0x, dy = p1y - p0y, dz = p1z - p0z;

    bool parx = fabsf(dx) < EPS_F;
    bool pary = fabsf(dy) < EPS_F;
    bool parz = fabsf(dz) < EPS_F;

    // ---- uniform xy window [uxy0, uxy1] ----
    float uxy0 = 0.0f, uxy1 = 1.0f;
    if (parx) {
        bool inside = (p0x >= 0.0f) && (p0x <= (float)NV);
        uxy0 = fmaxf(uxy0, inside ? 0.0f : BIG_F);
        uxy1 = fminf(uxy1, inside ? 1.0f : -BIG_F);
    } else {
        float t0 = (0.0f - p0x) / dx, t1 = ((float)NV - p0x) / dx;
        uxy0 = fmaxf(uxy0, fminf(t0, t1));
        uxy1 = fminf(uxy1, fmaxf(t0, t1));
    }
    if (pary) {
        bool inside = (p0y >= 0.0f) && (p0y <= (float)NV);
        uxy0 = fmaxf(uxy0, inside ? 0.0f : BIG_F);
        uxy1 = fminf(uxy1, inside ? 1.0f : -BIG_F);
    } else {
        float t0 = (0.0f - p0y) / dy, t1 = ((float)NV - p0y) / dy;
        uxy0 = fmaxf(uxy0, fminf(t0, t1));
        uxy1 = fminf(uxy1, fmaxf(t0, t1));
    }

    // ---- per-lane window: clip by z slab ----
    float tminl = uxy0, tmaxl = uxy1;
    if (parz) {
        bool inside = (p0z >= 0.0f) && (p0z <= (float)NV);
        tminl = fmaxf(tminl, inside ? 0.0f : BIG_F);
        tmaxl = fminf(tmaxl, inside ? 1.0f : -BIG_F);
    } else {
        float t0 = (0.0f - p0z) / dz, t1 = ((float)NV - p0z) / dz;
        tminl = fmaxf(tminl, fminf(t0, t1));
        tmaxl = fminf(tmaxl, fmaxf(t0, t1));
    }

    float acc = 0.0f;

    if (active && (uxy1 > uxy0)) {
        float span = (uxy1 - uxy0) * (1.0f / (float)SPLIT);
        float ta = uxy0 + (float)sub * span;
        float tb = (sub == SPLIT - 1) ? uxy1 : (uxy0 + (float)(sub + 1) * span);

        // ---- uniform xy-DDA init at t = ta ----
        float tx = BIG_F, ty = BIG_F;
        float adx = 0.0f, ady = 0.0f;
        int ix, iy;
        int ox = 0, oy = 0;

        if (!parx) {
            float invx = 1.0f / dx;
            adx = fabsf(invx);
            float q = p0x + ta * dx;
            int pl;
            if (dx > 0.0f) { pl = (int)floorf(q) + 1; ix = pl - 1; ox =  NVSQ; }
            else           { pl = (int)ceilf(q)  - 1; ix = pl;     ox = -NVSQ; }
            tx = ((float)pl - p0x) * invx;
        } else {
            ix = (int)floorf(p0x);
        }
        if (!pary) {
            float invy = 1.0f / dy;
            ady = fabsf(invy);
            float q = p0y + ta * dy;
            int pl;
            if (dy > 0.0f) { pl = (int)floorf(q) + 1; iy = pl - 1; oy =  NV; }
            else           { pl = (int)ceilf(q)  - 1; iy = pl;     oy = -NV; }
            ty = ((float)pl - p0y) * invy;
        } else {
            iy = (int)floorf(p0y);
        }

        int flatXY = ix * NVSQ + iy * NV;

        // ---- per-lane z-DDA init at this lane's clip start ----
        float cstart = fmaxf(ta, tminl);
        float tz = BIG_F, adz = 0.0f;
        int iz, oz = 0;
        if (!parz) {
            float invz = 1.0f / dz;
            adz = fabsf(invz);
            float q = p0z + cstart * dz;
            int pl;
            if (dz > 0.0f) { pl = (int)floorf(q) + 1; iz = pl - 1; oz =  1; }
            else           { pl = (int)ceilf(q)  - 1; iz = pl;     oz = -1; }
            tz = ((float)pl - p0z) * invz;
        } else {
            iz = (int)floorf(p0z);
        }

        float tcur = ta;
        const int MAXIT = 2 * (NV + 1) / SPLIT + 40;

        for (int it = 0; it < MAXIT; ++it) {
            if (!(tcur < tb)) break;                  // uniform exit

            float tn = fminf(fminf(tx, ty), tb);      // uniform segment end

            // lane-clipped segment [c0, c1), split at tz
            float c0  = fmaxf(tcur, tminl);
            float c1  = fminf(tn, tmaxl);
            float tzc = fminf(tz, c1);
            float dt0 = fmaxf(tzc - c0, 0.0f);
            float dt1 = fmaxf(c1 - fmaxf(tz, c0), 0.0f);

            unsigned a0 = (unsigned)(flatXY + iz);
            a0 = a0 < NV3 ? a0 : 0u;                  // dt==0 whenever OOB
            unsigned a1 = (unsigned)((int)a0 + oz);
            a1 = a1 < NV3 ? a1 : 0u;
            float v0 = vol[a0];
            float v1 = vol[a1];

            // advance uniform xy state
            bool sx = (tx <= tn), sy = (ty <= tn);
            tx += sx ? adx : 0.0f;
            ty += sy ? ady : 0.0f;
            flatXY += (sx ? ox : 0) + (sy ? oy : 0);

            // advance per-lane z state
            bool sz = (tz < tn);
            tz += sz ? adz : 0.0f;
            iz += sz ? oz : 0;

            acc = fmaf(dt1, v1, fmaf(dt0, v0, acc));
            tcur = tn;
        }
    }

    // ---- block reduction over the 8 sub-ranges: LDS [8][64], conflict-free ----
    __shared__ float part[SPLIT][RPB];
    part[sub][lane] = acc;
    __syncthreads();

    if (threadIdx.x < RPB && active) {
        float s = 0.0f;
        #pragma unroll
        for (int w = 0; w < SPLIT; ++w) s += part[w][threadIdx.x];
        out[r] = s * ray_len;
    }
}

extern "C" void kernel_launch(void* const* d_in, const int* in_sizes, int n_in,
                              void* d_out, int out_size, void* d_ws, size_t ws_size,
                              hipStream_t stream) {
    const float* vol  = (const float*)d_in[0];
    const float* M    = (const float*)d_in[1];
    const float* bvec = (const float*)d_in[2];
    const float* src  = (const float*)d_in[3];
    const float* dst  = (const float*)d_in[4];
    float* out = (float*)d_out;

    int n_ray = in_sizes[3] / 3;
    int nblk = (n_ray + RPB - 1) / RPB;
    dim3 block(512);
    dim3 grid((unsigned)nblk);
    hipLaunchKernelGGL(siddon_fwd_kernel, grid, block, 0, stream,
                       vol, M, bvec, src, dst, out, n_ray);
}

// Round 9
// 17.922 us; speedup vs baseline: 1.0874x; 1.0874x over previous
//
#include <hip/hip_runtime.h>
#include <math.h>

// Siddon exact forward projector — incremental (Amanatides-Woo) traversal.
// Block = 512 threads = 8 waves = 64 consecutive rays x 8 t-sub-ranges.
//
// Round-8 key insight: the harness's inter-replay fillBuffer writes 268 MB
// (> 256 MB L3), flushing the Infinity Cache before EVERY timed replay. The
// gather loop then walks the 8 MB volume through cold HBM misses, request-
// serialized (~500 lines/CU x ~900 cy) -> the ~17.6 us floor that was
// immune to MLP/occupancy/coalescing fixes (rounds 4-7 all null).
// Fix: Phase A streams the volume HBM->L2/L3 with ONE perfectly coalesced
// float4 load per thread (1024 blk x 512 thr x 16 B = exactly 8 MB, zero
// duplication, all lines in flight at sequential-BW rate ~1.5 us). Phase B
// (the round-6 DDA loop) then gathers against warm L3 / in-flight fills.

constexpr int      NV    = 128;
constexpr int      NVSQ  = NV * NV;
constexpr unsigned NV3   = (unsigned)NV * NV * NV;
constexpr float    EPS_F = 1e-12f;
constexpr float    BIG_F = 1e9f;
constexpr int      SPLIT = 8;    // sub-ranges per ray = waves per block
constexpr int      RPB   = 64;   // rays per block (= lanes per wave)

__global__ __launch_bounds__(512, 8)
void siddon_fwd_kernel(const float* __restrict__ vol,
                       const float* __restrict__ Mptr,
                       const float* __restrict__ bptr,
                       const float* __restrict__ src,
                       const float* __restrict__ dst,
                       float* __restrict__ out,
                       int n_ray)
{
    int lane = threadIdx.x & 63;
    int sub  = threadIdx.x >> 6;            // 0..7, one sub-range per wave

    // ---- Phase A: cooperative streaming warm of the volume (HBM -> L2/L3).
    // One float4 per thread, perfectly coalesced, zero duplication.
    float4 wrm = make_float4(0.f, 0.f, 0.f, 0.f);
    {
        size_t fi = ((size_t)blockIdx.x * blockDim.x + threadIdx.x) * 4u;
        if (fi + 3 < (size_t)NV3) {
            wrm = *reinterpret_cast<const float4*>(vol + fi);
        }
    }

    // ---- XCD-aware block swizzle (bijective when gridDim.x % 8 == 0) ----
    int bid = blockIdx.x;
    int nwg = gridDim.x;
    int lb  = ((nwg & 7) == 0) ? ((bid & 7) * (nwg >> 3) + (bid >> 3)) : bid;

    int r = lb * RPB + lane;
    bool active = (r < n_ray);
    int rc = active ? r : (n_ray - 1);      // clamped for loads

    // ---- uniform: M inverse via adjugate ----
    float m00 = Mptr[0], m01 = Mptr[1], m02 = Mptr[2];
    float m10 = Mptr[3], m11 = Mptr[4], m12 = Mptr[5];
    float m20 = Mptr[6], m21 = Mptr[7], m22 = Mptr[8];
    float det = m00*(m11*m22 - m12*m21) - m01*(m10*m22 - m12*m20)
              + m02*(m10*m21 - m11*m20);
    float idet = 1.0f / det;
    float i00 =  (m11*m22 - m12*m21)*idet;
    float i01 = -(m01*m22 - m02*m21)*idet;
    float i02 =  (m01*m12 - m02*m11)*idet;
    float i10 = -(m10*m22 - m12*m20)*idet;
    float i11 =  (m00*m22 - m02*m20)*idet;
    float i12 = -(m00*m12 - m02*m10)*idet;
    float i20 =  (m10*m21 - m11*m20)*idet;
    float i21 = -(m00*m21 - m01*m20)*idet;
    float i22 =  (m00*m11 - m01*m10)*idet;

    float bx = bptr[0], by = bptr[1], bz = bptr[2];

    float sxw = src[3*rc+0], syw = src[3*rc+1], szw = src[3*rc+2];
    float exw = dst[3*rc+0], eyw = dst[3*rc+1], ezw = dst[3*rc+2];

    float wxw = exw - sxw, wyw = eyw - syw, wzw = ezw - szw;
    float ray_len = sqrtf(wxw*wxw + wyw*wyw + wzw*wzw);

    float ux = sxw - bx, uy = syw - by, uz = szw - bz;
    float p0x = i00*ux + i01*uy + i02*uz;
    float p0y = i10*ux + i11*uy + i12*uz;
    float p0z = i20*ux + i21*uy + i22*uz;
    float vx = exw - bx, vy = eyw - by, vz = ezw - bz;
    float p1x = i00*vx + i01*vy + i02*vz;
    float p1y = i10*vx + i11*vy + i12*vz;
    float p1z = i20*vx + i21*vy + i22*vz;

    float dx = p1x - p0x, dy = p1y - p0y, dz = p1z - p0z;

    bool parx = fabsf(dx) < EPS_F;
    bool pary = fabsf(dy) < EPS_F;
    bool parz = fabsf(dz) < EPS_F;

    // ---- slab intersection ----
    float tmin = 0.0f, tmax = 1.0f;
    if (parx) {
        bool inside = (p0x >= 0.0f) && (p0x <= (float)NV);
        tmin = fmaxf(tmin, inside ? 0.0f : BIG_F);
        tmax = fminf(tmax, inside ? 1.0f : -BIG_F);
    } else {
        float t0 = (0.0f - p0x) / dx, t1 = ((float)NV - p0x) / dx;
        tmin = fmaxf(tmin, fminf(t0, t1));
        tmax = fminf(tmax, fmaxf(t0, t1));
    }
    if (pary) {
        bool inside = (p0y >= 0.0f) && (p0y <= (float)NV);
        tmin = fmaxf(tmin, inside ? 0.0f : BIG_F);
        tmax = fminf(tmax, inside ? 1.0f : -BIG_F);
    } else {
        float t0 = (0.0f - p0y) / dy, t1 = ((float)NV - p0y) / dy;
        tmin = fmaxf(tmin, fminf(t0, t1));
        tmax = fminf(tmax, fmaxf(t0, t1));
    }
    if (parz) {
        bool inside = (p0z >= 0.0f) && (p0z <= (float)NV);
        tmin = fmaxf(tmin, inside ? 0.0f : BIG_F);
        tmax = fminf(tmax, inside ? 1.0f : -BIG_F);
    } else {
        float t0 = (0.0f - p0z) / dz, t1 = ((float)NV - p0z) / dz;
        tmin = fmaxf(tmin, fminf(t0, t1));
        tmax = fminf(tmax, fmaxf(t0, t1));
    }

    // ---- keep the warm load alive; its waitcnt lands here, after ~60 VALU
    // of preamble, so the streaming fill overlaps the setup work. ----
    asm volatile("" :: "v"(wrm.x), "v"(wrm.y), "v"(wrm.z), "v"(wrm.w));

    float acc = 0.0f;

    if (active && (tmax > tmin)) {
        float span = (tmax - tmin) * (1.0f / (float)SPLIT);
        float ta = tmin + (float)sub * span;
        float tb = (sub == SPLIT - 1) ? tmax : (tmin + (float)(sub + 1) * span);

        // ---- DDA init at t = ta ----
        float tx = BIG_F, ty = BIG_F, tz = BIG_F;
        float adx = 0.0f, ady = 0.0f, adz = 0.0f;
        int ix, iy, iz;
        int ox = 0, oy = 0, oz = 0;

        if (!parx) {
            float invx = 1.0f / dx;
            adx = fabsf(invx);
            float q = p0x + ta * dx;
            int pl;
            if (dx > 0.0f) { pl = (int)floorf(q) + 1; ix = pl - 1; ox =  NVSQ; }
            else           { pl = (int)ceilf(q)  - 1; ix = pl;     ox = -NVSQ; }
            tx = ((float)pl - p0x) * invx;
        } else {
            ix = (int)floorf(p0x);
        }
        if (!pary) {
            float invy = 1.0f / dy;
            ady = fabsf(invy);
            float q = p0y + ta * dy;
            int pl;
            if (dy > 0.0f) { pl = (int)floorf(q) + 1; iy = pl - 1; oy =  NV; }
            else           { pl = (int)ceilf(q)  - 1; iy = pl;     oy = -NV; }
            ty = ((float)pl - p0y) * invy;
        } else {
            iy = (int)floorf(p0y);
        }
        if (!parz) {
            float invz = 1.0f / dz;
            adz = fabsf(invz);
            float q = p0z + ta * dz;
            int pl;
            if (dz > 0.0f) { pl = (int)floorf(q) + 1; iz = pl - 1; oz =  1; }
            else           { pl = (int)ceilf(q)  - 1; iz = pl;     oz = -1; }
            tz = ((float)pl - p0z) * invz;
        } else {
            iz = (int)floorf(p0z);
        }

        int flat = ix * NVSQ + iy * NV + iz;

        // ---- software-pipelined traversal (1-deep) ----
        unsigned uf = (unsigned)flat;
        bool vok = (uf < NV3);
        float vld = vol[uf < NV3 ? uf : (NV3 - 1u)];

        float tcur = ta;
        const int MAXIT = 3 * (NV + 1) / SPLIT + 32;

        for (int it = 0; it < MAXIT; ++it) {
            if (!(tcur < tb)) break;

            float tn = fminf(fminf(tx, ty), fminf(tz, tb));  // min3 + min
            float dt = tn - tcur;
            float dte = vok ? dt : 0.0f;                     // single gate

            bool sx = (tx <= tn), sy = (ty <= tn), sz = (tz <= tn);
            tx += sx ? adx : 0.0f;
            ty += sy ? ady : 0.0f;
            tz += sz ? adz : 0.0f;
            flat += (sx ? ox : 0) + (sy ? oy : 0) + (sz ? oz : 0);

            unsigned ufn = (unsigned)flat;
            bool vokn = (ufn < NV3);
            float vldn = vol[ufn < NV3 ? ufn : (NV3 - 1u)];  // issue next gather EARLY

            acc = fmaf(dte, vld, acc);                        // consume PREVIOUS gather

            vld = vldn;
            vok = vokn;
            tcur = tn;
        }
    }

    // ---- block reduction over the 8 sub-ranges: LDS [8][64], conflict-free ----
    __shared__ float part[SPLIT][RPB];
    part[sub][lane] = acc;
    __syncthreads();

    if (threadIdx.x < RPB && active) {
        float s = 0.0f;
        #pragma unroll
        for (int w = 0; w < SPLIT; ++w) s += part[w][threadIdx.x];
        out[r] = s * ray_len;
    }
}

extern "C" void kernel_launch(void* const* d_in, const int* in_sizes, int n_in,
                              void* d_out, int out_size, void* d_ws, size_t ws_size,
                              hipStream_t stream) {
    const float* vol  = (const float*)d_in[0];
    const float* M    = (const float*)d_in[1];
    const float* bvec = (const float*)d_in[2];
    const float* src  = (const float*)d_in[3];
    const float* dst  = (const float*)d_in[4];
    float* out = (float*)d_out;

    int n_ray = in_sizes[3] / 3;
    int nblk = (n_ray + RPB - 1) / RPB;
    dim3 block(512);
    dim3 grid((unsigned)nblk);
    hipLaunchKernelGGL(siddon_fwd_kernel, grid, block, 0, stream,
                       vol, M, bvec, src, dst, out, n_ray);
}

// Round 10
// 17.184 us; speedup vs baseline: 1.1341x; 1.0429x over previous
//
#include <hip/hip_runtime.h>
#include <math.h>

// Siddon exact forward projector — incremental (Amanatides-Woo) traversal.
// Block = 512 threads = 8 waves = 64 consecutive rays x 8 t-sub-ranges.
//
// Round-9: the kernel is VALU-issue-bound (at reduced DVFS clock) — every
// latency-side fix (MLP, occupancy, coalescing, cache warm) was null, so
// only the instruction count matters. Diet:
//  * hardware-bounds-checked buffer loads (SRD num_records = 8 MB): OOB
//    voffset returns 0.0 -> dt*0=0 replicates the reference's spatial
//    gating with ZERO per-iteration VALU (replaces cmp+clamp+gate+64-bit
//    address extend, ~5 VALU/iter).
//  * byte-offset DDA: flat index kept pre-scaled (x4); voffset used as-is.
//  * no XCD swizzle: identity block order round-robins detector rows
//    across XCDs -> balances the ~1.3x center-vs-edge work skew (r4 showed
//    L2 locality from the swizzle is worthless here).

constexpr int      NV    = 128;
constexpr int      NVSQ  = NV * NV;
constexpr unsigned NV3   = (unsigned)NV * NV * NV;
constexpr unsigned VBYTES = NV3 * 4u;
constexpr float    EPS_F = 1e-12f;
constexpr float    BIG_F = 1e9f;
constexpr int      SPLIT = 8;    // sub-ranges per ray = waves per block
constexpr int      RPB   = 64;   // rays per block (= lanes per wave)

#if __has_builtin(__builtin_amdgcn_make_buffer_rsrc) && __has_builtin(__builtin_amdgcn_raw_buffer_load_b32)
#define USE_BUFLOAD 1
#else
#define USE_BUFLOAD 0
#endif

__global__ __launch_bounds__(512, 8)
void siddon_fwd_kernel(const float* __restrict__ vol,
                       const float* __restrict__ Mptr,
                       const float* __restrict__ bptr,
                       const float* __restrict__ src,
                       const float* __restrict__ dst,
                       float* __restrict__ out,
                       int n_ray)
{
    int lane = threadIdx.x & 63;
    int sub  = threadIdx.x >> 6;            // 0..7, one sub-range per wave

    int r = blockIdx.x * RPB + lane;        // identity map: XCD round-robin
    bool active = (r < n_ray);
    int rc = active ? r : (n_ray - 1);      // clamped for loads

#if USE_BUFLOAD
    // SRD over the volume: stride=0 (raw), num_records=bytes, word3=raw-dword.
    // OOB (voffset+4 > VBYTES, incl. negative-as-huge-unsigned) loads return 0.
    auto vrsrc = __builtin_amdgcn_make_buffer_rsrc((void*)vol, (short)0,
                                                   (int)VBYTES, 0x00020000);
#endif

    // ---- uniform: M inverse via adjugate ----
    float m00 = Mptr[0], m01 = Mptr[1], m02 = Mptr[2];
    float m10 = Mptr[3], m11 = Mptr[4], m12 = Mptr[5];
    float m20 = Mptr[6], m21 = Mptr[7], m22 = Mptr[8];
    float det = m00*(m11*m22 - m12*m21) - m01*(m10*m22 - m12*m20)
              + m02*(m10*m21 - m11*m20);
    float idet = 1.0f / det;
    float i00 =  (m11*m22 - m12*m21)*idet;
    float i01 = -(m01*m22 - m02*m21)*idet;
    float i02 =  (m01*m12 - m02*m11)*idet;
    float i10 = -(m10*m22 - m12*m20)*idet;
    float i11 =  (m00*m22 - m02*m20)*idet;
    float i12 = -(m00*m12 - m02*m10)*idet;
    float i20 =  (m10*m21 - m11*m20)*idet;
    float i21 = -(m00*m21 - m01*m20)*idet;
    float i22 =  (m00*m11 - m01*m10)*idet;

    float bx = bptr[0], by = bptr[1], bz = bptr[2];

    float sxw = src[3*rc+0], syw = src[3*rc+1], szw = src[3*rc+2];
    float exw = dst[3*rc+0], eyw = dst[3*rc+1], ezw = dst[3*rc+2];

    float wxw = exw - sxw, wyw = eyw - syw, wzw = ezw - szw;
    float ray_len = sqrtf(wxw*wxw + wyw*wyw + wzw*wzw);

    float ux = sxw - bx, uy = syw - by, uz = szw - bz;
    float p0x = i00*ux + i01*uy + i02*uz;
    float p0y = i10*ux + i11*uy + i12*uz;
    float p0z = i20*ux + i21*uy + i22*uz;
    float vx = exw - bx, vy = eyw - by, vz = ezw - bz;
    float p1x = i00*vx + i01*vy + i02*vz;
    float p1y = i10*vx + i11*vy + i12*vz;
    float p1z = i20*vx + i21*vy + i22*vz;

    float dx = p1x - p0x, dy = p1y - p0y, dz = p1z - p0z;

    bool parx = fabsf(dx) < EPS_F;
    bool pary = fabsf(dy) < EPS_F;
    bool parz = fabsf(dz) < EPS_F;

    // ---- slab intersection (per-lane window folds x, y AND z exits) ----
    float tmin = 0.0f, tmax = 1.0f;
    if (parx) {
        bool inside = (p0x >= 0.0f) && (p0x <= (float)NV);
        tmin = fmaxf(tmin, inside ? 0.0f : BIG_F);
        tmax = fminf(tmax, inside ? 1.0f : -BIG_F);
    } else {
        float t0 = (0.0f - p0x) / dx, t1 = ((float)NV - p0x) / dx;
        tmin = fmaxf(tmin, fminf(t0, t1));
        tmax = fminf(tmax, fmaxf(t0, t1));
    }
    if (pary) {
        bool inside = (p0y >= 0.0f) && (p0y <= (float)NV);
        tmin = fmaxf(tmin, inside ? 0.0f : BIG_F);
        tmax = fminf(tmax, inside ? 1.0f : -BIG_F);
    } else {
        float t0 = (0.0f - p0y) / dy, t1 = ((float)NV - p0y) / dy;
        tmin = fmaxf(tmin, fminf(t0, t1));
        tmax = fminf(tmax, fmaxf(t0, t1));
    }
    if (parz) {
        bool inside = (p0z >= 0.0f) && (p0z <= (float)NV);
        tmin = fmaxf(tmin, inside ? 0.0f : BIG_F);
        tmax = fminf(tmax, inside ? 1.0f : -BIG_F);
    } else {
        float t0 = (0.0f - p0z) / dz, t1 = ((float)NV - p0z) / dz;
        tmin = fmaxf(tmin, fminf(t0, t1));
        tmax = fminf(tmax, fmaxf(t0, t1));
    }

    float acc = 0.0f;

    if (active && (tmax > tmin)) {
        float span = (tmax - tmin) * (1.0f / (float)SPLIT);
        float ta = tmin + (float)sub * span;
        float tb = (sub == SPLIT - 1) ? tmax : (tmin + (float)(sub + 1) * span);

        // ---- DDA init at t = ta (byte-scaled flat index) ----
        float tx = BIG_F, ty = BIG_F, tz = BIG_F;
        float adx = 0.0f, ady = 0.0f, adz = 0.0f;
        int ix, iy, iz;
        int ox = 0, oy = 0, oz = 0;

        if (!parx) {
            float invx = 1.0f / dx;
            adx = fabsf(invx);
            float q = p0x + ta * dx;
            int pl;
            if (dx > 0.0f) { pl = (int)floorf(q) + 1; ix = pl - 1; ox =  NVSQ*4; }
            else           { pl = (int)ceilf(q)  - 1; ix = pl;     ox = -NVSQ*4; }
            tx = ((float)pl - p0x) * invx;
        } else {
            ix = (int)floorf(p0x);
        }
        if (!pary) {
            float invy = 1.0f / dy;
            ady = fabsf(invy);
            float q = p0y + ta * dy;
            int pl;
            if (dy > 0.0f) { pl = (int)floorf(q) + 1; iy = pl - 1; oy =  NV*4; }
            else           { pl = (int)ceilf(q)  - 1; iy = pl;     oy = -NV*4; }
            ty = ((float)pl - p0y) * invy;
        } else {
            iy = (int)floorf(p0y);
        }
        if (!parz) {
            float invz = 1.0f / dz;
            adz = fabsf(invz);
            float q = p0z + ta * dz;
            int pl;
            if (dz > 0.0f) { pl = (int)floorf(q) + 1; iz = pl - 1; oz =  4; }
            else           { pl = (int)ceilf(q)  - 1; iz = pl;     oz = -4; }
            tz = ((float)pl - p0z) * invz;
        } else {
            iz = (int)floorf(p0z);
        }

        int flat = (ix * NVSQ + iy * NV + iz) * 4;   // BYTE offset

        // ---- software-pipelined traversal (1-deep) ----
#if USE_BUFLOAD
        float vld = __builtin_bit_cast(float,
            __builtin_amdgcn_raw_buffer_load_b32(vrsrc, (unsigned)flat, 0, 0));
#else
        unsigned uf0 = (unsigned)flat >> 2;
        float vld = (uf0 < NV3) ? vol[uf0] : 0.0f;
#endif

        float tcur = ta;
        const int MAXIT = 3 * (NV + 1) / SPLIT + 32;

        for (int it = 0; it < MAXIT; ++it) {
            if (!(tcur < tb)) break;

            float tn = fminf(fminf(tx, ty), fminf(tz, tb));  // min3 + min
            float dt = tn - tcur;

            bool sx = (tx <= tn), sy = (ty <= tn), sz = (tz <= tn);
            tx += sx ? adx : 0.0f;
            ty += sy ? ady : 0.0f;
            tz += sz ? adz : 0.0f;
            flat += (sx ? ox : 0) + (sy ? oy : 0) + (sz ? oz : 0);

#if USE_BUFLOAD
            float vldn = __builtin_bit_cast(float,
                __builtin_amdgcn_raw_buffer_load_b32(vrsrc, (unsigned)flat, 0, 0));
#else
            unsigned ufn = (unsigned)flat >> 2;
            float vldn = (ufn < NV3) ? vol[ufn] : 0.0f;
#endif

            acc = fmaf(dt, vld, acc);   // OOB load returned 0 -> dt*0 = 0

            vld = vldn;
            tcur = tn;
        }
    }

    // ---- block reduction over the 8 sub-ranges: LDS [8][64], conflict-free ----
    __shared__ float part[SPLIT][RPB];
    part[sub][lane] = acc;
    __syncthreads();

    if (threadIdx.x < RPB && active) {
        float s = 0.0f;
        #pragma unroll
        for (int w = 0; w < SPLIT; ++w) s += part[w][threadIdx.x];
        out[r] = s * ray_len;
    }
}

extern "C" void kernel_launch(void* const* d_in, const int* in_sizes, int n_in,
                              void* d_out, int out_size, void* d_ws, size_t ws_size,
                              hipStream_t stream) {
    const float* vol  = (const float*)d_in[0];
    const float* M    = (const float*)d_in[1];
    const float* bvec = (const float*)d_in[2];
    const float* src  = (const float*)d_in[3];
    const float* dst  = (const float*)d_in[4];
    float* out = (float*)d_out;

    int n_ray = in_sizes[3] / 3;
    int nblk = (n_ray + RPB - 1) / RPB;
    dim3 block(512);
    dim3 grid((unsigned)nblk);
    hipLaunchKernelGGL(siddon_fwd_kernel, grid, block, 0, stream,
                       vol, M, bvec, src, dst, out, n_ray);
}